// Round 1
// baseline (754.630 us; speedup 1.0000x reference)
//
#include <hip/hip_runtime.h>
#include <hip/hip_bf16.h>
#include <math.h>

// ---------------------------------------------------------------------------
// GPT block fused pipeline, bf16 MFMA. B=4,S=2048,D=1024,H=16,HD=64.
// ws layout (bytes):
//   W1t  @ 0         : 3072x1024 bf16 (W_attn^T)   6291456
//   W2t  @ 6291456   : 1024x1024 bf16 (W_cproj^T)  2097152
//   W3t  @ 8388608   : 4096x1024 bf16 (W_fc^T)     8388608
//   W4t  @ 16777216  : 1024x4096 bf16 (W_mproj^T)  8388608
//   h    @ 25165824  : 8192x1024 bf16 (ln1 out, later ln2 out)
//   aout @ 41943040  : 8192x1024 bf16 (attention out)
//   big  @ 58720256  : 8192x3072 bf16 qkv, later 8192x4096 bf16 fc-act
//   total 125829120 bytes.  x2 (residual after attn) lives in d_out (fp32).
// ---------------------------------------------------------------------------

typedef __attribute__((ext_vector_type(8))) short short8;
typedef __attribute__((ext_vector_type(4))) float floatx4;

#define MFMA16(a, b, c) __builtin_amdgcn_mfma_f32_16x16x32_bf16((a), (b), (c), 0, 0, 0)

__device__ __forceinline__ short f2bf(float f) {
    union { float f; unsigned u; } a; a.f = f;
    unsigned r = a.u + 0x7fffu + ((a.u >> 16) & 1u);   // round-to-nearest-even
    return (short)(r >> 16);
}

__device__ __forceinline__ float gelu_f(float x) {
    return 0.5f * x * (1.0f + tanhf(0.7978845608028654f * (x + 0.044715f * x * x * x)));
}

__device__ __forceinline__ void gload_lds16(const short* g, short* l) {
    __builtin_amdgcn_global_load_lds((const __attribute__((address_space(1))) void*)g,
                                     (__attribute__((address_space(3))) void*)l, 16, 0, 0);
}

// ---------------- transpose + cast fp32 W[K][N] -> bf16 Wt[N][K] -------------
__global__ void tcast_kernel(const float* __restrict__ W, short* __restrict__ Wt,
                             int K, int N) {
    __shared__ float tile[32][33];
    const int bx = blockIdx.x * 32;  // n
    const int by = blockIdx.y * 32;  // k
    const int tx = threadIdx.x;      // 0..31
    const int ty = threadIdx.y;      // 0..7
#pragma unroll
    for (int i = 0; i < 32; i += 8)
        tile[ty + i][tx] = W[(size_t)(by + ty + i) * N + bx + tx];
    __syncthreads();
#pragma unroll
    for (int i = 0; i < 32; i += 8)
        Wt[(size_t)(bx + ty + i) * K + by + tx] = f2bf(tile[tx][ty + i]);
}

// ---------------- LayerNorm: fp32 [8192][1024] -> bf16 ----------------------
__global__ __launch_bounds__(256) void ln_kernel(const float* __restrict__ x,
                                                 const float* __restrict__ w,
                                                 const float* __restrict__ b,
                                                 short* __restrict__ out) {
    const int row = blockIdx.x;
    const int t = threadIdx.x;
    const float4 v = ((const float4*)(x + (size_t)row * 1024))[t];
    float s = v.x + v.y + v.z + v.w;
    float s2 = v.x * v.x + v.y * v.y + v.z * v.z + v.w * v.w;
#pragma unroll
    for (int d = 32; d >= 1; d >>= 1) {
        s += __shfl_xor(s, d, 64);
        s2 += __shfl_xor(s2, d, 64);
    }
    __shared__ float red[8];
    const int wid = t >> 6, lane = t & 63;
    if (lane == 0) { red[wid * 2] = s; red[wid * 2 + 1] = s2; }
    __syncthreads();
    s = red[0] + red[2] + red[4] + red[6];
    s2 = red[1] + red[3] + red[5] + red[7];
    const float mean = s * (1.f / 1024.f);
    const float var = s2 * (1.f / 1024.f) - mean * mean;
    const float rstd = rsqrtf(var + 1e-5f);
    const float4 wv = ((const float4*)w)[t];
    const float4 bv = ((const float4*)b)[t];
    union { ushort4 u; short sa[4]; } ov;
    ov.sa[0] = f2bf(wv.x * ((v.x - mean) * rstd) + bv.x);
    ov.sa[1] = f2bf(wv.y * ((v.y - mean) * rstd) + bv.y);
    ov.sa[2] = f2bf(wv.z * ((v.z - mean) * rstd) + bv.z);
    ov.sa[3] = f2bf(wv.w * ((v.w - mean) * rstd) + bv.w);
    ((ushort4*)(out + (size_t)row * 1024))[t] = ov.u;
}

// ---------------- GEMM: C[M][N] = A[M][K] @ Bt[N][K]^T + bias, epilogues -----
// EPI 0: store bf16.  EPI 1: gelu -> bf16.  EPI 2: + res(fp32) -> fp32.
template <int EPI>
__global__ __launch_bounds__(256) void gemm_kernel(
    const short* __restrict__ A, const short* __restrict__ Bt,
    const float* __restrict__ bias, const float* __restrict__ res,
    void* __restrict__ Cout, int M, int N, int K) {
    __shared__ __align__(16) short As[128][32];
    __shared__ __align__(16) short Bs[128][32];

    const int tid = threadIdx.x;
    const int wid = tid >> 6;
    const int lane = tid & 63;
    const int quad = lane >> 4;
    const int l16 = lane & 15;
    const int wm = (wid >> 1) * 64;
    const int wn = (wid & 1) * 64;
    const int m0 = blockIdx.y * 128;
    const int n0 = blockIdx.x * 128;

    const int lr = lane >> 2;        // row within 16-row wave slab
    const int lc = (lane & 3) * 8;   // short offset within 32-wide row

    floatx4 acc[4][4] = {};

    const short* ga0 = A + (size_t)(m0 + wid * 16 + lr) * K + lc;
    const short* ga1 = A + (size_t)(m0 + 64 + wid * 16 + lr) * K + lc;
    const short* gb0 = Bt + (size_t)(n0 + wid * 16 + lr) * K + lc;
    const short* gb1 = Bt + (size_t)(n0 + 64 + wid * 16 + lr) * K + lc;
    short* lA0 = &As[wid * 16][0];
    short* lA1 = &As[64 + wid * 16][0];
    short* lB0 = &Bs[wid * 16][0];
    short* lB1 = &Bs[64 + wid * 16][0];

    for (int k0 = 0; k0 < K; k0 += 32) {
        gload_lds16(ga0 + k0, lA0);
        gload_lds16(ga1 + k0, lA1);
        gload_lds16(gb0 + k0, lB0);
        gload_lds16(gb1 + k0, lB1);
        __syncthreads();
        short8 af[4], bf[4];
#pragma unroll
        for (int mt = 0; mt < 4; mt++)
            af[mt] = *(const short8*)&As[wm + mt * 16 + l16][quad * 8];
#pragma unroll
        for (int nt = 0; nt < 4; nt++)
            bf[nt] = *(const short8*)&Bs[wn + nt * 16 + l16][quad * 8];
#pragma unroll
        for (int mt = 0; mt < 4; mt++)
#pragma unroll
            for (int nt = 0; nt < 4; nt++)
                acc[mt][nt] = MFMA16(af[mt], bf[nt], acc[mt][nt]);
        __syncthreads();
    }
#pragma unroll
    for (int nt = 0; nt < 4; nt++) {
        const int col = n0 + wn + nt * 16 + l16;
        const float bv = bias[col];
#pragma unroll
        for (int mt = 0; mt < 4; mt++) {
#pragma unroll
            for (int r = 0; r < 4; r++) {
                const int row = m0 + wm + mt * 16 + quad * 4 + r;
                const size_t idx = (size_t)row * N + col;
                float v = acc[mt][nt][r] + bv;
                if constexpr (EPI == 0) {
                    ((short*)Cout)[idx] = f2bf(v);
                } else if constexpr (EPI == 1) {
                    ((short*)Cout)[idx] = f2bf(gelu_f(v));
                } else {
                    ((float*)Cout)[idx] = v + res[idx];
                }
            }
        }
    }
}

// ---------------- causal flash attention -------------------------------------
// qkv bf16 [B=4][S=2048][3072] (q|k|v each 1024 = 16 heads x 64)
// out bf16 [B][S][1024].  Grid: (16 q-tiles of 128, 64 bh). Block 256 (4 waves
// x 32 q-rows). K/V tiles of 64 keys staged in LDS, V transposed.
__global__ __launch_bounds__(256) void attn_kernel(const short* __restrict__ qkv,
                                                   short* __restrict__ aout) {
    __shared__ __align__(16) short Ks[64][72];
    __shared__ __align__(16) short Vt[64][72];
    __shared__ __align__(16) short Ps[4][32][72];

    const int tid = threadIdx.x;
    const int wid = tid >> 6;
    const int lane = tid & 63;
    const int quad = lane >> 4;
    const int l16 = lane & 15;

    const int q0 = blockIdx.x * 128;
    const int bh = blockIdx.y;
    const int b = bh >> 4;
    const int h = bh & 15;

    const short* base = qkv + (size_t)b * 2048 * 3072 + h * 64;
    const int qrow_base = q0 + wid * 32;

    short8 qf[2][2];
#pragma unroll
    for (int mt = 0; mt < 2; mt++)
#pragma unroll
        for (int ks = 0; ks < 2; ks++)
            qf[mt][ks] = *(const short8*)(base +
                (size_t)(qrow_base + mt * 16 + l16) * 3072 + ks * 32 + quad * 8);

    floatx4 o[2][4] = {};
    float mrow[2][4], lrow[2][4];
#pragma unroll
    for (int mt = 0; mt < 2; mt++)
#pragma unroll
        for (int r = 0; r < 4; r++) { mrow[mt][r] = -1e30f; lrow[mt][r] = 0.f; }

    const int nkt = q0 / 64 + 2;   // causal: tiles up to and including diagonal
    for (int kt = 0; kt < nkt; kt++) {
        const int kt0 = kt * 64;
        {   // stage K[64][64] and V^T[64][64] cooperatively
            const int r = tid >> 2;
            const int cg = (tid & 3) * 16;
            const short* krow = base + (size_t)(kt0 + r) * 3072 + 1024 + cg;
            const short* vrow = base + (size_t)(kt0 + r) * 3072 + 2048 + cg;
            *(uint4*)&Ks[r][cg] = ((const uint4*)krow)[0];
            *(uint4*)&Ks[r][cg + 8] = ((const uint4*)krow)[1];
            short vv[16];
            *(uint4*)&vv[0] = ((const uint4*)vrow)[0];
            *(uint4*)&vv[8] = ((const uint4*)vrow)[1];
#pragma unroll
            for (int j = 0; j < 16; j++) Vt[cg + j][r] = vv[j];
        }
        __syncthreads();
        const bool active = (kt0 <= qrow_base + 31);
        if (active) {
            floatx4 sa[2][4] = {};
#pragma unroll
            for (int ks = 0; ks < 2; ks++) {
                short8 kf[4];
#pragma unroll
                for (int nt = 0; nt < 4; nt++)
                    kf[nt] = *(const short8*)&Ks[nt * 16 + l16][ks * 32 + quad * 8];
#pragma unroll
                for (int mt = 0; mt < 2; mt++)
#pragma unroll
                    for (int nt = 0; nt < 4; nt++)
                        sa[mt][nt] = MFMA16(qf[mt][ks], kf[nt], sa[mt][nt]);
            }
            const bool needmask = (kt0 + 63) > qrow_base;
#pragma unroll
            for (int mt = 0; mt < 2; mt++)
#pragma unroll
                for (int nt = 0; nt < 4; nt++)
#pragma unroll
                    for (int r = 0; r < 4; r++) {
                        float sv = sa[mt][nt][r] * 0.125f;   // 1/sqrt(64)
                        if (needmask) {
                            const int kn = kt0 + nt * 16 + l16;
                            const int qq = qrow_base + mt * 16 + quad * 4 + r;
                            if (kn > qq) sv = -1e30f;
                        }
                        sa[mt][nt][r] = sv;
                    }
#pragma unroll
            for (int mt = 0; mt < 2; mt++) {
#pragma unroll
                for (int r = 0; r < 4; r++) {
                    float mx = fmaxf(fmaxf(sa[mt][0][r], sa[mt][1][r]),
                                     fmaxf(sa[mt][2][r], sa[mt][3][r]));
#pragma unroll
                    for (int d = 1; d < 16; d <<= 1) mx = fmaxf(mx, __shfl_xor(mx, d, 64));
                    const float mnew = fmaxf(mrow[mt][r], mx);
                    const float alpha = __expf(mrow[mt][r] - mnew);
                    mrow[mt][r] = mnew;
                    float psum = 0.f;
#pragma unroll
                    for (int nt = 0; nt < 4; nt++) {
                        const float p = __expf(sa[mt][nt][r] - mnew);
                        sa[mt][nt][r] = p;
                        psum += p;
                    }
#pragma unroll
                    for (int d = 1; d < 16; d <<= 1) psum += __shfl_xor(psum, d, 64);
                    lrow[mt][r] = lrow[mt][r] * alpha + psum;
#pragma unroll
                    for (int dt = 0; dt < 4; dt++) o[mt][dt][r] *= alpha;
#pragma unroll
                    for (int nt = 0; nt < 4; nt++)
                        Ps[wid][mt * 16 + quad * 4 + r][nt * 16 + l16] = f2bf(sa[mt][nt][r]);
                }
            }
            __asm__ volatile("s_waitcnt lgkmcnt(0)" ::: "memory");
#pragma unroll
            for (int ks = 0; ks < 2; ks++) {
                short8 pf[2], vf[4];
#pragma unroll
                for (int mt = 0; mt < 2; mt++)
                    pf[mt] = *(const short8*)&Ps[wid][mt * 16 + l16][ks * 32 + quad * 8];
#pragma unroll
                for (int dt = 0; dt < 4; dt++)
                    vf[dt] = *(const short8*)&Vt[dt * 16 + l16][ks * 32 + quad * 8];
#pragma unroll
                for (int mt = 0; mt < 2; mt++)
#pragma unroll
                    for (int dt = 0; dt < 4; dt++)
                        o[mt][dt] = MFMA16(pf[mt], vf[dt], o[mt][dt]);
            }
        }
        __syncthreads();
    }
#pragma unroll
    for (int mt = 0; mt < 2; mt++)
#pragma unroll
        for (int dt = 0; dt < 4; dt++)
#pragma unroll
            for (int r = 0; r < 4; r++) {
                const float v = o[mt][dt][r] / lrow[mt][r];
                const int q = qrow_base + mt * 16 + quad * 4 + r;
                aout[(size_t)(b * 2048 + q) * 1024 + h * 64 + dt * 16 + l16] = f2bf(v);
            }
}

// ---------------------------------------------------------------------------
extern "C" void kernel_launch(void* const* d_in, const int* in_sizes, int n_in,
                              void* d_out, int out_size, void* d_ws, size_t ws_size,
                              hipStream_t stream) {
    const float* x       = (const float*)d_in[0];
    const float* ln1_w   = (const float*)d_in[1];
    const float* ln1_b   = (const float*)d_in[2];
    const float* W_attn  = (const float*)d_in[3];
    const float* b_attn  = (const float*)d_in[4];
    const float* W_cproj = (const float*)d_in[5];
    const float* b_cproj = (const float*)d_in[6];
    const float* ln2_w   = (const float*)d_in[7];
    const float* ln2_b   = (const float*)d_in[8];
    const float* W_fc    = (const float*)d_in[9];
    const float* b_fc    = (const float*)d_in[10];
    const float* W_mproj = (const float*)d_in[11];
    const float* b_mproj = (const float*)d_in[12];

    char* ws = (char*)d_ws;
    short* W1t  = (short*)(ws + 0);
    short* W2t  = (short*)(ws + 6291456);
    short* W3t  = (short*)(ws + 8388608);
    short* W4t  = (short*)(ws + 16777216);
    short* h    = (short*)(ws + 25165824);
    short* aout = (short*)(ws + 41943040);
    short* big  = (short*)(ws + 58720256);   // qkv, later fc-act
    float* x2   = (float*)d_out;             // residual after attn lives in d_out
    float* out  = (float*)d_out;

    dim3 tb(32, 8);
    hipLaunchKernelGGL(tcast_kernel, dim3(96, 32), tb, 0, stream, W_attn, W1t, 1024, 3072);
    hipLaunchKernelGGL(tcast_kernel, dim3(32, 32), tb, 0, stream, W_cproj, W2t, 1024, 1024);
    hipLaunchKernelGGL(tcast_kernel, dim3(128, 32), tb, 0, stream, W_fc, W3t, 1024, 4096);
    hipLaunchKernelGGL(tcast_kernel, dim3(32, 128), tb, 0, stream, W_mproj, W4t, 4096, 1024);

    hipLaunchKernelGGL(ln_kernel, dim3(8192), dim3(256), 0, stream, x, ln1_w, ln1_b, h);

    hipLaunchKernelGGL((gemm_kernel<0>), dim3(24, 64), dim3(256), 0, stream,
                       h, W1t, b_attn, (const float*)nullptr, (void*)big, 8192, 3072, 1024);

    hipLaunchKernelGGL(attn_kernel, dim3(16, 64), dim3(256), 0, stream, big, aout);

    hipLaunchKernelGGL((gemm_kernel<2>), dim3(8, 64), dim3(256), 0, stream,
                       aout, W2t, b_cproj, x, (void*)x2, 8192, 1024, 1024);

    hipLaunchKernelGGL(ln_kernel, dim3(8192), dim3(256), 0, stream, x2, ln2_w, ln2_b, h);

    hipLaunchKernelGGL((gemm_kernel<1>), dim3(32, 64), dim3(256), 0, stream,
                       h, W3t, b_fc, (const float*)nullptr, (void*)big, 8192, 4096, 1024);

    hipLaunchKernelGGL((gemm_kernel<2>), dim3(8, 64), dim3(256), 0, stream,
                       big, W4t, b_mproj, x2, (void*)out, 8192, 1024, 4096);
}

// Round 3
// 608.982 us; speedup vs baseline: 1.2392x; 1.2392x over previous
//
#include <hip/hip_runtime.h>
#include <hip/hip_bf16.h>
#include <math.h>

// ---------------------------------------------------------------------------
// GPT block fused pipeline, bf16 MFMA. B=4,S=2048,D=1024,H=16,HD=64.
// ws layout (bytes):
//   W1t  @ 0         : 3072x1024 bf16 (W_attn^T)   6291456
//   W2t  @ 6291456   : 1024x1024 bf16 (W_cproj^T)  2097152
//   W3t  @ 8388608   : 4096x1024 bf16 (W_fc^T)     8388608
//   W4t  @ 16777216  : 1024x4096 bf16 (W_mproj^T)  8388608
//   h    @ 25165824  : 8192x1024 bf16 (ln1 out, later ln2 out)
//   aout @ 41943040  : 8192x1024 bf16 (attention out)
//   big  @ 58720256  : 8192x3072 bf16 qkv, later 8192x4096 bf16 fc-act
//   total 125829120 bytes.  x2 (residual after attn) lives in d_out (fp32).
// ---------------------------------------------------------------------------

typedef __attribute__((ext_vector_type(8))) short short8;
typedef __attribute__((ext_vector_type(4))) float floatx4;

#define MFMA16(a, b, c) __builtin_amdgcn_mfma_f32_16x16x32_bf16((a), (b), (c), 0, 0, 0)

__device__ __forceinline__ short f2bf(float f) {
    union { float f; unsigned u; } a; a.f = f;
    unsigned r = a.u + 0x7fffu + ((a.u >> 16) & 1u);   // round-to-nearest-even
    return (short)(r >> 16);
}

__device__ __forceinline__ float fexp2(float x) {
    return exp2f(x);   // maps to v_exp_f32
}

__device__ __forceinline__ float gelu_f(float x) {
    return 0.5f * x * (1.0f + tanhf(0.7978845608028654f * (x + 0.044715f * x * x * x)));
}

__device__ __forceinline__ void gload_lds16(const short* g, short* l) {
    __builtin_amdgcn_global_load_lds((const __attribute__((address_space(1))) void*)g,
                                     (__attribute__((address_space(3))) void*)l, 16, 0, 0);
}

// ---------------- transpose + cast fp32 W[K][N] -> bf16 Wt[N][K] -------------
__global__ void tcast_kernel(const float* __restrict__ W, short* __restrict__ Wt,
                             int K, int N) {
    __shared__ float tile[32][33];
    const int bx = blockIdx.x * 32;  // n
    const int by = blockIdx.y * 32;  // k
    const int tx = threadIdx.x;      // 0..31
    const int ty = threadIdx.y;      // 0..7
#pragma unroll
    for (int i = 0; i < 32; i += 8)
        tile[ty + i][tx] = W[(size_t)(by + ty + i) * N + bx + tx];
    __syncthreads();
#pragma unroll
    for (int i = 0; i < 32; i += 8)
        Wt[(size_t)(bx + ty + i) * K + by + tx] = f2bf(tile[tx][ty + i]);
}

// ---------------- LayerNorm: fp32 [8192][1024] -> bf16 ----------------------
__global__ __launch_bounds__(256) void ln_kernel(const float* __restrict__ x,
                                                 const float* __restrict__ w,
                                                 const float* __restrict__ b,
                                                 short* __restrict__ out) {
    const int row = blockIdx.x;
    const int t = threadIdx.x;
    const float4 v = ((const float4*)(x + (size_t)row * 1024))[t];
    float s = v.x + v.y + v.z + v.w;
    float s2 = v.x * v.x + v.y * v.y + v.z * v.z + v.w * v.w;
#pragma unroll
    for (int d = 32; d >= 1; d >>= 1) {
        s += __shfl_xor(s, d, 64);
        s2 += __shfl_xor(s2, d, 64);
    }
    __shared__ float red[8];
    const int wid = t >> 6, lane = t & 63;
    if (lane == 0) { red[wid * 2] = s; red[wid * 2 + 1] = s2; }
    __syncthreads();
    s = red[0] + red[2] + red[4] + red[6];
    s2 = red[1] + red[3] + red[5] + red[7];
    const float mean = s * (1.f / 1024.f);
    const float var = s2 * (1.f / 1024.f) - mean * mean;
    const float rstd = rsqrtf(var + 1e-5f);
    const float4 wv = ((const float4*)w)[t];
    const float4 bv = ((const float4*)b)[t];
    union { ushort4 u; short sa[4]; } ov;
    ov.sa[0] = f2bf(wv.x * ((v.x - mean) * rstd) + bv.x);
    ov.sa[1] = f2bf(wv.y * ((v.y - mean) * rstd) + bv.y);
    ov.sa[2] = f2bf(wv.z * ((v.z - mean) * rstd) + bv.z);
    ov.sa[3] = f2bf(wv.w * ((v.w - mean) * rstd) + bv.w);
    ((ushort4*)(out + (size_t)row * 1024))[t] = ov.u;
}

// ---------------- GEMM: C[M][N] = A[M][K] @ Bt[N][K]^T + bias, epilogues -----
// EPI 0: store bf16.  EPI 1: gelu -> bf16.  EPI 2: + res(fp32) -> fp32.
template <int EPI>
__global__ __launch_bounds__(256) void gemm_kernel(
    const short* __restrict__ A, const short* __restrict__ Bt,
    const float* __restrict__ bias, const float* __restrict__ res,
    void* __restrict__ Cout, int M, int N, int K) {
    __shared__ __align__(16) short As[128][32];
    __shared__ __align__(16) short Bs[128][32];

    const int tid = threadIdx.x;
    const int wid = tid >> 6;
    const int lane = tid & 63;
    const int quad = lane >> 4;
    const int l16 = lane & 15;
    const int wm = (wid >> 1) * 64;
    const int wn = (wid & 1) * 64;
    const int m0 = blockIdx.y * 128;
    const int n0 = blockIdx.x * 128;

    const int lr = lane >> 2;        // row within 16-row wave slab
    const int lc = (lane & 3) * 8;   // short offset within 32-wide row

    floatx4 acc[4][4] = {};

    const short* ga0 = A + (size_t)(m0 + wid * 16 + lr) * K + lc;
    const short* ga1 = A + (size_t)(m0 + 64 + wid * 16 + lr) * K + lc;
    const short* gb0 = Bt + (size_t)(n0 + wid * 16 + lr) * K + lc;
    const short* gb1 = Bt + (size_t)(n0 + 64 + wid * 16 + lr) * K + lc;
    short* lA0 = &As[wid * 16][0];
    short* lA1 = &As[64 + wid * 16][0];
    short* lB0 = &Bs[wid * 16][0];
    short* lB1 = &Bs[64 + wid * 16][0];

    for (int k0 = 0; k0 < K; k0 += 32) {
        gload_lds16(ga0 + k0, lA0);
        gload_lds16(ga1 + k0, lA1);
        gload_lds16(gb0 + k0, lB0);
        gload_lds16(gb1 + k0, lB1);
        __syncthreads();
        short8 af[4], bf[4];
#pragma unroll
        for (int mt = 0; mt < 4; mt++)
            af[mt] = *(const short8*)&As[wm + mt * 16 + l16][quad * 8];
#pragma unroll
        for (int nt = 0; nt < 4; nt++)
            bf[nt] = *(const short8*)&Bs[wn + nt * 16 + l16][quad * 8];
#pragma unroll
        for (int mt = 0; mt < 4; mt++)
#pragma unroll
            for (int nt = 0; nt < 4; nt++)
                acc[mt][nt] = MFMA16(af[mt], bf[nt], acc[mt][nt]);
        __syncthreads();
    }
#pragma unroll
    for (int nt = 0; nt < 4; nt++) {
        const int col = n0 + wn + nt * 16 + l16;
        const float bv = bias[col];
#pragma unroll
        for (int mt = 0; mt < 4; mt++) {
#pragma unroll
            for (int r = 0; r < 4; r++) {
                const int row = m0 + wm + mt * 16 + quad * 4 + r;
                const size_t idx = (size_t)row * N + col;
                float v = acc[mt][nt][r] + bv;
                if constexpr (EPI == 0) {
                    ((short*)Cout)[idx] = f2bf(v);
                } else if constexpr (EPI == 1) {
                    ((short*)Cout)[idx] = f2bf(gelu_f(v));
                } else {
                    ((float*)Cout)[idx] = v + res[idx];
                }
            }
        }
    }
}

// ---------------- causal flash attention (S^T formulation) -------------------
// qkv bf16 [B=4][S=2048][3072] (q|k|v each 1024 = 16 heads x 64)
// out bf16 [B][S][1024].
// S^T = K·Q^T via mfma(A=K, B=Q): C-layout puts q on lanes (col=l16), keys on
// quad*4+r -> softmax over keys is in-register + 2 shuffles; per-q state is
// per-lane. P^T (C-layout) feeds PV directly: for a 32-key chunk each lane
// holds keys {c*32+quad*4+r} u {c*32+16+quad*4+r} = exactly the 8 B-operand
// slots of mfma_16x16x32 under the key remap key(quad*8+j) = c*32 +
// (j<4 ? quad*4+j : 16+quad*4+j-4); the V^T A-operand is gathered from LDS at
// those same keys. No P LDS round-trip, no V transpose, only the verified
// 16x16x32 builtin. O^T -> O via per-wave LDS transpose at the end.
__global__ __launch_bounds__(256) void attn_kernel(const short* __restrict__ qkv,
                                                   short* __restrict__ aout) {
    __shared__ __align__(16) short smem[9216];   // Ks[64][72] | Vs[64][68]; reused as Ow
    short* Ks = smem;               // stride 72
    short* Vs = smem + 64 * 72;     // stride 68: u16 column reads conflict-free

    const int tid = threadIdx.x;
    const int wid = tid >> 6;
    const int lane = tid & 63;
    const int quad = lane >> 4;
    const int l16 = lane & 15;

    const int qtile = 15 - blockIdx.y;      // longest (most k-tiles) blocks first
    const int q0 = qtile * 128;
    const int bh = blockIdx.x;
    const int b = bh >> 4;
    const int h = bh & 15;

    const short* base = qkv + (size_t)b * 2048 * 3072 + h * 64;
    const int qrow_base = q0 + wid * 32;

    // Q fragments (B-operand of S^T): lane n=l16 -> q row, k = ks*32 + quad*8+j
    short8 qf[2][2];
#pragma unroll
    for (int qt = 0; qt < 2; qt++)
#pragma unroll
        for (int ks = 0; ks < 2; ks++)
            qf[qt][ks] = *(const short8*)(base +
                (size_t)(qrow_base + qt * 16 + l16) * 3072 + ks * 32 + quad * 8);

    floatx4 o[4][2] = {};           // O^T: [dt][qt], row d=dt*16+quad*4+r, col q=l16
    float mrow[2] = {-1e30f, -1e30f};
    float lrow[2] = {0.f, 0.f};
    const float SCL = 0.125f * 1.44269504f;  // 1/sqrt(64) * log2(e); softmax in base-2

    const int nkt = qtile * 2 + 2;
    for (int kt = 0; kt < nkt; kt++) {
        const int kt0 = kt * 64;
        {   // stage K[64][64] and V[64][64] (row-major, padded, coalesced)
            const int r = tid >> 2;
            const int cg = (tid & 3) * 16;
            const short* krow = base + (size_t)(kt0 + r) * 3072 + 1024 + cg;
            const short* vrow = base + (size_t)(kt0 + r) * 3072 + 2048 + cg;
            *(uint4*)&Ks[r * 72 + cg] = ((const uint4*)krow)[0];
            *(uint4*)&Ks[r * 72 + cg + 8] = ((const uint4*)krow)[1];
            *(uint2*)&Vs[r * 68 + cg] = ((const uint2*)vrow)[0];
            *(uint2*)&Vs[r * 68 + cg + 4] = ((const uint2*)vrow)[1];
            *(uint2*)&Vs[r * 68 + cg + 8] = ((const uint2*)vrow)[2];
            *(uint2*)&Vs[r * 68 + cg + 12] = ((const uint2*)vrow)[3];
        }
        __syncthreads();
        if (kt0 <= qrow_base + 31) {
            // S^T[key][q]: A = K rows (lane=key), B = Q rows (lane=q)
            floatx4 st[4][2] = {};
#pragma unroll
            for (int kti = 0; kti < 4; kti++) {
                const short8 kf0 = *(const short8*)&Ks[(kti * 16 + l16) * 72 + quad * 8];
                const short8 kf1 = *(const short8*)&Ks[(kti * 16 + l16) * 72 + 32 + quad * 8];
#pragma unroll
                for (int qt = 0; qt < 2; qt++) {
                    st[kti][qt] = MFMA16(kf0, qf[qt][0], st[kti][qt]);
                    st[kti][qt] = MFMA16(kf1, qf[qt][1], st[kti][qt]);
                }
            }
            const bool needmask = (kt0 + 63) > qrow_base;
            short8 pk[2][2];   // [chunk c][qt]: B-operand for PV (packed kti pair)
#pragma unroll
            for (int qt = 0; qt < 2; qt++) {
                const int q = qrow_base + qt * 16 + l16;
#pragma unroll
                for (int kti = 0; kti < 4; kti++)
#pragma unroll
                    for (int r = 0; r < 4; r++) {
                        float v = st[kti][qt][r] * SCL;
                        if (needmask && (kt0 + kti * 16 + quad * 4 + r) > q) v = -1e30f;
                        st[kti][qt][r] = v;
                    }
                float mx = -1e30f;
#pragma unroll
                for (int kti = 0; kti < 4; kti++)
#pragma unroll
                    for (int r = 0; r < 4; r++) mx = fmaxf(mx, st[kti][qt][r]);
                mx = fmaxf(mx, __shfl_xor(mx, 16, 64));
                mx = fmaxf(mx, __shfl_xor(mx, 32, 64));
                const float mnew = fmaxf(mrow[qt], mx);
                const float alpha = fexp2(mrow[qt] - mnew);
                mrow[qt] = mnew;
                float ps = 0.f;
#pragma unroll
                for (int kti = 0; kti < 4; kti++)
#pragma unroll
                    for (int r = 0; r < 4; r++) {
                        const float p = fexp2(st[kti][qt][r] - mnew);
                        st[kti][qt][r] = p;
                        ps += p;
                    }
                ps += __shfl_xor(ps, 16, 64);
                ps += __shfl_xor(ps, 32, 64);
                lrow[qt] = lrow[qt] * alpha + ps;
#pragma unroll
                for (int dt = 0; dt < 4; dt++) o[dt][qt] *= alpha;
#pragma unroll
                for (int kti = 0; kti < 4; kti++)
#pragma unroll
                    for (int r = 0; r < 4; r++)
                        pk[kti >> 1][qt][(kti & 1) * 4 + r] = f2bf(st[kti][qt][r]);
            }
            // PV: O^T += V^T · P^T as K=32 MFMA with remapped logical k.
#pragma unroll
            for (int c = 0; c < 2; c++)
#pragma unroll
                for (int dt = 0; dt < 4; dt++) {
                    short8 vf;
#pragma unroll
                    for (int j = 0; j < 4; j++) {
                        vf[j]     = Vs[(c * 32 + quad * 4 + j) * 68 + dt * 16 + l16];
                        vf[4 + j] = Vs[(c * 32 + 16 + quad * 4 + j) * 68 + dt * 16 + l16];
                    }
                    o[dt][0] = MFMA16(vf, pk[c][0], o[dt][0]);
                    o[dt][1] = MFMA16(vf, pk[c][1], o[dt][1]);
                }
        }
        __syncthreads();
    }
    // epilogue: normalize, per-wave transpose O^T->O through LDS, coalesced store
    short* Ow = smem + wid * (32 * 72);   // [32 q][72 stride]
    const float rl0 = 1.0f / lrow[0];
    const float rl1 = 1.0f / lrow[1];
#pragma unroll
    for (int dt = 0; dt < 4; dt++)
#pragma unroll
        for (int r = 0; r < 4; r++) {
            Ow[(l16) * 72 + dt * 16 + quad * 4 + r] = f2bf(o[dt][0][r] * rl0);
            Ow[(16 + l16) * 72 + dt * 16 + quad * 4 + r] = f2bf(o[dt][1][r] * rl1);
        }
    __asm__ volatile("s_waitcnt lgkmcnt(0)" ::: "memory");
    {
        const int ql = lane >> 1;          // 0..31
        const int h2 = lane & 1;           // which 64B half of the row
        short* orow = aout + (size_t)(b * 2048 + q0 + wid * 32 + ql) * 1024 + h * 64 + h2 * 32;
#pragma unroll
        for (int s = 0; s < 4; s++)
            *(uint4*)(orow + s * 8) = *(const uint4*)&Ow[ql * 72 + h2 * 32 + s * 8];
    }
}

// ---------------------------------------------------------------------------
extern "C" void kernel_launch(void* const* d_in, const int* in_sizes, int n_in,
                              void* d_out, int out_size, void* d_ws, size_t ws_size,
                              hipStream_t stream) {
    const float* x       = (const float*)d_in[0];
    const float* ln1_w   = (const float*)d_in[1];
    const float* ln1_b   = (const float*)d_in[2];
    const float* W_attn  = (const float*)d_in[3];
    const float* b_attn  = (const float*)d_in[4];
    const float* W_cproj = (const float*)d_in[5];
    const float* b_cproj = (const float*)d_in[6];
    const float* ln2_w   = (const float*)d_in[7];
    const float* ln2_b   = (const float*)d_in[8];
    const float* W_fc    = (const float*)d_in[9];
    const float* b_fc    = (const float*)d_in[10];
    const float* W_mproj = (const float*)d_in[11];
    const float* b_mproj = (const float*)d_in[12];

    char* ws = (char*)d_ws;
    short* W1t  = (short*)(ws + 0);
    short* W2t  = (short*)(ws + 6291456);
    short* W3t  = (short*)(ws + 8388608);
    short* W4t  = (short*)(ws + 16777216);
    short* h    = (short*)(ws + 25165824);
    short* aout = (short*)(ws + 41943040);
    short* big  = (short*)(ws + 58720256);   // qkv, later fc-act
    float* x2   = (float*)d_out;             // residual after attn lives in d_out
    float* out  = (float*)d_out;

    dim3 tb(32, 8);
    hipLaunchKernelGGL(tcast_kernel, dim3(96, 32), tb, 0, stream, W_attn, W1t, 1024, 3072);
    hipLaunchKernelGGL(tcast_kernel, dim3(32, 32), tb, 0, stream, W_cproj, W2t, 1024, 1024);
    hipLaunchKernelGGL(tcast_kernel, dim3(128, 32), tb, 0, stream, W_fc, W3t, 1024, 4096);
    hipLaunchKernelGGL(tcast_kernel, dim3(32, 128), tb, 0, stream, W_mproj, W4t, 4096, 1024);

    hipLaunchKernelGGL(ln_kernel, dim3(8192), dim3(256), 0, stream, x, ln1_w, ln1_b, h);

    hipLaunchKernelGGL((gemm_kernel<0>), dim3(24, 64), dim3(256), 0, stream,
                       h, W1t, b_attn, (const float*)nullptr, (void*)big, 8192, 3072, 1024);

    hipLaunchKernelGGL(attn_kernel, dim3(64, 16), dim3(256), 0, stream, big, aout);

    hipLaunchKernelGGL((gemm_kernel<2>), dim3(8, 64), dim3(256), 0, stream,
                       aout, W2t, b_cproj, x, (void*)x2, 8192, 1024, 1024);

    hipLaunchKernelGGL(ln_kernel, dim3(8192), dim3(256), 0, stream, x2, ln2_w, ln2_b, h);

    hipLaunchKernelGGL((gemm_kernel<1>), dim3(32, 64), dim3(256), 0, stream,
                       h, W3t, b_fc, (const float*)nullptr, (void*)big, 8192, 4096, 1024);

    hipLaunchKernelGGL((gemm_kernel<2>), dim3(8, 64), dim3(256), 0, stream,
                       big, W4t, b_mproj, x2, (void*)out, 8192, 1024, 4096);
}